// Round 8
// baseline (181.815 us; speedup 1.0000x reference)
//
#include <hip/hip_runtime.h>
#include <hip/hip_fp16.h>
#include <stdint.h>

// StyleHyperLinear on MI355X.
// out[b,t,o] = b_base[o] + sum_d x[b,t,d] * Weff[b,o,d]
// Weff[b] = w_base + mat_b[b] @ mat_a[b]   (LoRA folded; ALPHA=1)
// v4.1: fix compile error (xf must be ext_vector f32x4, not HIP float4).
//     2-phase double-buffered pipeline: issue-early next x loads + W DMA,
//     compute cur, write-late X cvt+ds_write, ONE barrier per K-step.

#define NB 8
#define NT 4096
#define DIN 512
#define DOUT 512
#define NSTYLE 256
#define RANK 8
#define NLORA ((DIN + DOUT) * RANK)  // 8192

typedef _Float16 f16x8 __attribute__((ext_vector_type(8)));
typedef float f32x4 __attribute__((ext_vector_type(4)));

// ---------------- kernel 1: h = silu(style @ w_h1^T + b_h1) ----------------
__global__ void k_hyper1(const float* __restrict__ style,
                         const float* __restrict__ w_h1,
                         const float* __restrict__ b_h1,
                         float* __restrict__ h) {
  const int b = blockIdx.x;
  const int j = threadIdx.x;
  __shared__ float s[NSTYLE];
  s[j] = style[b * NSTYLE + j];
  __syncthreads();
  const float4* wrow = (const float4*)(w_h1 + (size_t)j * NSTYLE);
  float acc = b_h1[j];
#pragma unroll 8
  for (int k = 0; k < NSTYLE / 4; ++k) {
    float4 w4 = wrow[k];
    acc += s[4 * k + 0] * w4.x + s[4 * k + 1] * w4.y + s[4 * k + 2] * w4.z +
           s[4 * k + 3] * w4.w;
  }
  h[b * NSTYLE + j] = acc / (1.f + expf(-acc));
}

// ---------------- kernel 2: raw = h @ w_h2^T + b_h2 (coalesced) -----------
__global__ __launch_bounds__(256) void k_hyper2(const float* __restrict__ h,
                                                const float* __restrict__ w_h2,
                                                const float* __restrict__ b_h2,
                                                float* __restrict__ raw) {
  __shared__ float hs[NB * NSTYLE];  // 8KB
  const int t = threadIdx.x;
#pragma unroll
  for (int i = 0; i < NB * NSTYLE / 256; ++i) hs[i * 256 + t] = h[i * 256 + t];
  __syncthreads();
  const int w = t >> 6, lane = t & 63;
  const int n = blockIdx.x * 4 + w;
  float4 w4 = *(const float4*)(w_h2 + (size_t)n * NSTYLE + lane * 4);
  float acc[NB];
#pragma unroll
  for (int b = 0; b < NB; ++b) {
    float4 hb = *(const float4*)(&hs[b * NSTYLE + lane * 4]);
    acc[b] = hb.x * w4.x + hb.y * w4.y + hb.z * w4.z + hb.w * w4.w;
#pragma unroll
    for (int m = 32; m > 0; m >>= 1) acc[b] += __shfl_xor(acc[b], m);
  }
  if (lane == 0) {
    const float bb = b_h2[n];
#pragma unroll
    for (int b = 0; b < NB; ++b) raw[(size_t)b * NLORA + n] = acc[b] + bb;
  }
}

// ---------------- kernel 3: Weff fragments -------------------------------
// Whf element layout (per batch b, region 512*512 fp16):
//   flat = cg*8192 + kkg*512 + lane*8 + j
//   holds Weff[b][o = cg*16 + (lane&15)][k = kkg*32 + (lane>>4)*8 + j]
__global__ void k_weff(const float* __restrict__ raw,
                       const float* __restrict__ w_base,
                       _Float16* __restrict__ Whf) {
  const int cg = blockIdx.x;  // 32 col-groups of 16 output rows
  const int b = blockIdx.y;
  const int t = threadIdx.x;
  __shared__ float Als[RANK * DIN];     // 16KB, mat_a flat r*512+d
  __shared__ float Wbs[16 * 516];       // 33KB, padded stride 516
  __shared__ float Bls[16][RANK];
  const float* rb = raw + (size_t)b * NLORA;
#pragma unroll
  for (int i = 0; i < 4; ++i)
    *(float4*)(&Als[(i * 256 + t) * 4]) = *(const float4*)(&rb[(i * 256 + t) * 4]);
#pragma unroll
  for (int i = 0; i < 8; ++i) {
    int fi = i * 256 + t;           // float4 id, 2048 total
    int oo = fi >> 7, d4 = fi & 127;
    float4 v = *(const float4*)(&w_base[((size_t)(cg * 16 + oo)) * DIN + d4 * 4]);
    *(float4*)(&Wbs[oo * 516 + d4 * 4]) = v;
  }
  if (t < 16 * RANK) {
    int oo = t >> 3, r = t & 7;
    Bls[oo][r] = rb[DIN * RANK + (cg * 16 + oo) * RANK + r];
  }
  __syncthreads();
  const int lane = t & 63;
  const int oo = lane & 15;
  const int koff = ((lane >> 4) & 3) * 8;
  float br[RANK];
#pragma unroll
  for (int r = 0; r < RANK; ++r) br[r] = Bls[oo][r];
  _Float16* dst = Whf + (size_t)b * (DOUT * DIN) + cg * 8192;
#pragma unroll
  for (int i = 0; i < 4; ++i) {
    const int q = i * 256 + t;       // [0,1024)
    const int kkg = q >> 6;          // [0,16)
    const int kb = kkg * 32 + koff;
    f16x8 v;
#pragma unroll
    for (int j = 0; j < 8; ++j) {
      float a = Wbs[oo * 516 + kb + j];
#pragma unroll
      for (int r = 0; r < RANK; ++r) a += br[r] * Als[r * DIN + kb + j];
      v[j] = (_Float16)a;
    }
    *(f16x8*)(dst + (size_t)q * 8) = v;
  }
}

// ---------------- kernel 4: main GEMM, 2-phase pipelined -----------------
// 128x128 tile, BK=64, 4 waves (2x2, 64x64 subtile each, 4x4 frags).
// Double-buffered Xs (reg-staged fp32->fp16, XOR swizzle both sides) and
// Ws (global_load_lds, fragment-linear). Per step: issue next x loads +
// next W DMA -> compute cur -> cvt+ds_write next X -> ONE barrier.
// x loads issued BEFORE DMA so the x-consume waits vmcnt(4), keeping the
// 4 DMAs in flight until the barrier (they span the whole compute phase).
#define BM 128
#define BN 128
#define BK 64

__global__ __launch_bounds__(256) void k_gemm(
    const float* __restrict__ x, const _Float16* __restrict__ Whf,
    const float* __restrict__ b_base, float* __restrict__ out) {
  const int id = blockIdx.x;
  const int b = id & 7;          // (id%8) -> XCD: W_b stays L2-local
  const int nt = (id >> 3) & 3;  // [0,4)
  const int mt = id >> 5;        // [0,32)
  const int t = threadIdx.x;
  const int lane = t & 63;
  const int wave = t >> 6;
  const int wr = wave >> 1, wc = wave & 1;
  const int l16 = lane & 15, lq = lane >> 4;

  __shared__ _Float16 Xs[2][BM * BK];  // 2 x 16KB, swizzled [row][k]
  __shared__ _Float16 Ws[2][BN * BK];  // 2 x 16KB, fragment-linear

  const float* xb = x + ((size_t)b * NT + (size_t)mt * BM) * DIN;
  const _Float16* wbt = Whf + (size_t)b * (DOUT * DIN) + (size_t)(nt * 8) * 8192;

  f32x4 acc[4][4];
#pragma unroll
  for (int m = 0; m < 4; ++m)
#pragma unroll
    for (int n = 0; n < 4; ++n)
#pragma unroll
      for (int j = 0; j < 4; ++j) acc[m][n][j] = 0.f;

  // X stage map: chunk p = i*256+t -> row=p>>3, o8=p&7 (8 thr cover a 256B
  // row-slice contiguously). LDS byte = (row*128 + o8*16) ^ ((row&7)<<4).
  // W DMA map: chunk c = i*256+t -> cgr=c>>7, kkr=(c>>6)&1, e=c&63;
  //   src = wbt + cgr*8192 + (step*2+kkr)*512 + e*8; dst linear c*16.

  f32x4 xf[4][2];

  // ---- prologue: stage step 0 into buffers [0] ----
#pragma unroll
  for (int i = 0; i < 4; ++i) {
    const int p = i * 256 + t;
    const float* src = xb + (size_t)(p >> 3) * DIN + (p & 7) * 8;
    xf[i][0] = *(const f32x4*)(src);
    xf[i][1] = *(const f32x4*)(src + 4);
  }
#pragma unroll
  for (int i = 0; i < 4; ++i) {
    const int c = i * 256 + t;
    const _Float16* g = wbt + (size_t)(c >> 7) * 8192 +
                        (size_t)((c >> 6) & 1) * 512 + (c & 63) * 8;
    __builtin_amdgcn_global_load_lds(
        (const __attribute__((address_space(1))) void*)g,
        (__attribute__((address_space(3))) void*)((char*)Ws[0] +
                                                  (i * 256 + wave * 64) * 16),
        16, 0, 0);
  }
#pragma unroll
  for (int i = 0; i < 4; ++i) {
    const int p = i * 256 + t;
    const int row = p >> 3, o8 = p & 7;
    f16x8 hh;
    hh[0] = (_Float16)xf[i][0][0]; hh[1] = (_Float16)xf[i][0][1];
    hh[2] = (_Float16)xf[i][0][2]; hh[3] = (_Float16)xf[i][0][3];
    hh[4] = (_Float16)xf[i][1][0]; hh[5] = (_Float16)xf[i][1][1];
    hh[6] = (_Float16)xf[i][1][2]; hh[7] = (_Float16)xf[i][1][3];
    const int byte = (row * 128 + o8 * 16) ^ ((row & 7) << 4);
    *(f16x8*)((char*)Xs[0] + byte) = hh;
  }
  __syncthreads();

  // ---- main loop: one barrier per step ----
  for (int step = 0; step < DIN / BK; ++step) {
    const int cur = step & 1;
    const bool pf = step < DIN / BK - 1;
    // issue-early: next x loads (older in vmcnt), then next W DMA
    if (pf) {
#pragma unroll
      for (int i = 0; i < 4; ++i) {
        const int p = i * 256 + t;
        const float* src =
            xb + (size_t)(p >> 3) * DIN + (step + 1) * BK + (p & 7) * 8;
        xf[i][0] = *(const f32x4*)(src);
        xf[i][1] = *(const f32x4*)(src + 4);
      }
#pragma unroll
      for (int i = 0; i < 4; ++i) {
        const int c = i * 256 + t;
        const _Float16* g = wbt + (size_t)(c >> 7) * 8192 +
                            (size_t)((step + 1) * 2 + ((c >> 6) & 1)) * 512 +
                            (c & 63) * 8;
        __builtin_amdgcn_global_load_lds(
            (const __attribute__((address_space(1))) void*)g,
            (__attribute__((address_space(3))) void*)((char*)Ws[cur ^ 1] +
                                                      (i * 256 + wave * 64) * 16),
            16, 0, 0);
      }
    }
    // compute on buffers [cur]
#pragma unroll
    for (int kk = 0; kk < 2; ++kk) {
      f16x8 af[4], bf[4];
#pragma unroll
      for (int m = 0; m < 4; ++m) {
        const int row = wr * 64 + m * 16 + l16;
        const int byte = (row * 128 + (kk * 4 + lq) * 16) ^ ((row & 7) << 4);
        af[m] = *(const f16x8*)((const char*)Xs[cur] + byte);
      }
#pragma unroll
      for (int n = 0; n < 4; ++n)
        bf[n] = *(const f16x8*)((const char*)Ws[cur] +
                                (((wc * 4 + n) * 2 + kk) * 1024 + lane * 16));
#pragma unroll
      for (int m = 0; m < 4; ++m)
#pragma unroll
        for (int n = 0; n < 4; ++n)
          acc[m][n] = __builtin_amdgcn_mfma_f32_16x16x32_f16(af[m], bf[n],
                                                             acc[m][n], 0, 0, 0);
    }
    // write-late: cvt + ds_write next X tile (waits x loads = vmcnt(4),
    // leaving the 4 DMAs in flight until the barrier)
    if (pf) {
#pragma unroll
      for (int i = 0; i < 4; ++i) {
        const int p = i * 256 + t;
        const int row = p >> 3, o8 = p & 7;
        f16x8 hh;
        hh[0] = (_Float16)xf[i][0][0]; hh[1] = (_Float16)xf[i][0][1];
        hh[2] = (_Float16)xf[i][0][2]; hh[3] = (_Float16)xf[i][0][3];
        hh[4] = (_Float16)xf[i][1][0]; hh[5] = (_Float16)xf[i][1][1];
        hh[6] = (_Float16)xf[i][1][2]; hh[7] = (_Float16)xf[i][1][3];
        const int byte = (row * 128 + o8 * 16) ^ ((row & 7) << 4);
        *(f16x8*)((char*)Xs[cur ^ 1] + byte) = hh;
      }
    }
    __syncthreads();
  }

  // ---- epilogue: D mapping col=lane&15, row=(lane>>4)*4+reg ----
  float bv[4];
#pragma unroll
  for (int n = 0; n < 4; ++n)
    bv[n] = b_base[nt * BN + wc * 64 + n * 16 + l16];

#pragma unroll
  for (int m = 0; m < 4; ++m) {
#pragma unroll
    for (int j = 0; j < 4; ++j) {
      const int r = mt * BM + wr * 64 + m * 16 + lq * 4 + j;
      float* orow = out + ((size_t)b * NT + r) * DOUT + nt * BN;
#pragma unroll
      for (int n = 0; n < 4; ++n)
        orow[wc * 64 + n * 16 + l16] = acc[m][n][j] + bv[n];
    }
  }
}

// ---------------- launcher ----------------
extern "C" void kernel_launch(void* const* d_in, const int* in_sizes, int n_in,
                              void* d_out, int out_size, void* d_ws,
                              size_t ws_size, hipStream_t stream) {
  const float* x = (const float*)d_in[0];
  const float* style = (const float*)d_in[1];
  const float* w_base = (const float*)d_in[2];
  const float* b_base = (const float*)d_in[3];
  const float* w_h1 = (const float*)d_in[4];
  const float* b_h1 = (const float*)d_in[5];
  const float* w_h2 = (const float*)d_in[6];
  const float* b_h2 = (const float*)d_in[7];
  float* out = (float*)d_out;

  // workspace: h (8KB) | raw (256KB) | Whf fp16 (4MB)
  char* ws = (char*)d_ws;
  float* h = (float*)ws;
  float* raw = (float*)(ws + 8192);
  _Float16* Whf = (_Float16*)(ws + 8192 + 262144);

  k_hyper1<<<NB, NSTYLE, 0, stream>>>(style, w_h1, b_h1, h);
  k_hyper2<<<NLORA / 4, 256, 0, stream>>>(h, w_h2, b_h2, raw);
  k_weff<<<dim3(DOUT / 16, NB), 256, 0, stream>>>(raw, w_base, Whf);
  k_gemm<<<(NT / BM) * (DOUT / BN) * NB, 256, 0, stream>>>(x, Whf, b_base, out);
}